// Round 8
// baseline (229.821 us; speedup 1.0000x reference)
//
#include <hip/hip_runtime.h>
#include <stdint.h>

typedef unsigned short u16;
typedef __bf16 bf16x8 __attribute__((ext_vector_type(8)));
typedef float fx4 __attribute__((ext_vector_type(4)));
typedef float fx16 __attribute__((ext_vector_type(16)));

// ---------------- helpers ----------------

__device__ __forceinline__ u16 f2bf(float f) {
    unsigned int u = __float_as_uint(f);
    u += 0x7fffu + ((u >> 16) & 1u);   // RNE
    return (u16)(u >> 16);
}

__device__ __forceinline__ bf16x8 ld8(const u16* p) {
    return __builtin_bit_cast(bf16x8, *(const int4*)p);
}

// pack two fp32 -> packed bf16 dword (round-half-up)
__device__ __forceinline__ uint32_t pk2bf(float lo, float hi) {
    uint32_t a = __float_as_uint(lo) + 0x8000u;
    uint32_t b = __float_as_uint(hi) + 0x8000u;
    return __builtin_amdgcn_perm(b, a, 0x07060302u);
}

// async global->LDS, 16B per lane: HW writes lds_base + lane*16
typedef __attribute__((address_space(3))) uint32_t lds_u32;
typedef __attribute__((address_space(1))) const uint32_t glb_u32;
__device__ __forceinline__ void glds16(const u16* g, u16* l) {
    __builtin_amdgcn_global_load_lds((glb_u32*)g, (lds_u32*)l, 16, 0, 0);
}

// ---------------- kernel 0a: cast x -> bf16 ----------------

__global__ __launch_bounds__(256) void cast_x_kernel(const float* __restrict__ x,
                                                     u16* __restrict__ xb) {
    int idx = blockIdx.x * 256 + threadIdx.x;   // 8 elems per thread
    const float4* p = (const float4*)(x + (size_t)idx * 8);
    float4 a = p[0], b = p[1];
    int4 v;
    v.x = (int)pk2bf(a.x, a.y); v.y = (int)pk2bf(a.z, a.w);
    v.z = (int)pk2bf(b.x, b.y); v.w = (int)pk2bf(b.z, b.w);
    *(int4*)(xb + (size_t)idx * 8) = v;
}

// ---------------- kernel 0b: transpose + cast both weight matrices ----------------
// grid (32, 8): bx<24 -> w_qkv [512][1536], else w_out [512][512]

__global__ __launch_bounds__(256) void transpose_cast_kernel(const float* __restrict__ w_qkv,
                                                             u16* __restrict__ wqkv_t,
                                                             const float* __restrict__ w_out,
                                                             u16* __restrict__ wout_t) {
    __shared__ float T[64][65];
    int t = threadIdx.x;
    int bx = blockIdx.x;
    const float* in; u16* out; int NR = 512, NC;
    if (bx < 24) { in = w_qkv; out = wqkv_t; NC = 1536; }
    else         { in = w_out; out = wout_t; NC = 512; bx -= 24; }
    int i0 = blockIdx.y * 64, j0 = bx * 64;
    int r = t >> 4, cc = t & 15;
#pragma unroll
    for (int j = 0; j < 4; ++j) {
        int row = r + j * 16;
        float4 v = *(const float4*)(in + (size_t)(i0 + row) * NC + j0 + cc * 4);
        T[row][cc * 4 + 0] = v.x; T[row][cc * 4 + 1] = v.y;
        T[row][cc * 4 + 2] = v.z; T[row][cc * 4 + 3] = v.w;
    }
    __syncthreads();
#pragma unroll
    for (int j = 0; j < 4; ++j) {
        int jr = r + j * 16;
        unsigned int u0 = f2bf(T[cc * 4 + 0][jr]) | ((unsigned int)f2bf(T[cc * 4 + 1][jr]) << 16);
        unsigned int u1 = f2bf(T[cc * 4 + 2][jr]) | ((unsigned int)f2bf(T[cc * 4 + 3][jr]) << 16);
        uint2 u; u.x = u0; u.y = u1;
        *(uint2*)(out + (size_t)(j0 + jr) * NR + i0 + cc * 4) = u;
    }
}

// ---------------- GEMM: C[M,Ncols] = A[M,512] * Bt[Ncols,512]^T ----------------
// A bf16; A and B staged via global_load_lds. XCD-aware block swizzle.
// MODE 0: epilogue restages C-tile in LDS in fragment-blob order -> Qf/Kf/Vf.
// MODE 1: -> d_out fp32 + bias.

#define QSCALE 0.180336880f   // (1/8) * log2(e): logits in log2 domain

template<int MODE>
__global__ __launch_bounds__(256) void gemm_kernel(const u16* __restrict__ A,
                                                   const u16* __restrict__ Bt,
                                                   u16* __restrict__ Qf,
                                                   u16* __restrict__ Kf,
                                                   u16* __restrict__ Vf,
                                                   const float* __restrict__ bias,
                                                   float* __restrict__ Out,
                                                   int Ncols) {
    __shared__ __align__(16) u16 Sh[16384];        // As=Sh[0..4096), Bs=Sh[4096..8192); epilogue uses all
    int tid = threadIdx.x;
    int w = tid >> 6, lane = tid & 63;
    int m16 = lane & 15, quad = lane >> 4;
    int ntn = Ncols / 128;
    // XCD swizzle: consecutive blocks (same XCD, round-robin heuristic) share a row-tile
    int g = blockIdx.x;
    int xcd = g & 7, j = g >> 3;
    int by = xcd + 8 * (j / ntn);
    int bx = j % ntn;
    int r0 = by * 128, c0 = bx * 128;
    int wr = w >> 1, wc = w & 1;
    int lrow = lane >> 2, lchk = (lane & 3) * 8;   // glds lane mapping

    fx4 acc[4][4] = {};

    for (int k0 = 0; k0 < 512; k0 += 32) {
        __syncthreads();
#pragma unroll
        for (int jj = 0; jj < 2; ++jj) {
            int rw = jj * 64 + w * 16;             // wave-uniform row base
            glds16(A  + (size_t)(r0 + rw + lrow) * 512 + k0 + lchk, &Sh[rw * 32]);
            glds16(Bt + (size_t)(c0 + rw + lrow) * 512 + k0 + lchk, &Sh[4096 + rw * 32]);
        }
        __syncthreads();
        bf16x8 af[4], bfr[4];
#pragma unroll
        for (int t = 0; t < 4; ++t) {
            af[t]  = ld8(&Sh[(wr * 64 + t * 16 + m16) * 32 + quad * 8]);
            bfr[t] = ld8(&Sh[4096 + (wc * 64 + t * 16 + m16) * 32 + quad * 8]);
        }
#pragma unroll
        for (int mt = 0; mt < 4; ++mt)
#pragma unroll
            for (int nt = 0; nt < 4; ++nt)
                acc[mt][nt] = __builtin_amdgcn_mfma_f32_16x16x32_bf16(af[mt], bfr[nt], acc[mt][nt], 0, 0, 0);
    }

    if (MODE == 0) {
        // ---- epilogue: C-tile -> LDS in fragment-blob order -> coalesced stores ----
        int sec = c0 >> 9;                         // tile-uniform: 0=q 1=k 2=v
        __syncthreads();
        if (sec <= 1) {
            float sc = (sec == 0) ? QSCALE : 1.0f;
#pragma unroll
            for (int mt = 0; mt < 4; ++mt)
#pragma unroll
                for (int nt = 0; nt < 4; ++nt) {
                    int lb = wc * 16 + (wr * 2 + (mt >> 1)) * 4 + nt;
                    int eb = lb * 512 + (m16 >> 3) * 256 + ((mt & 1) * 16 + quad * 4) * 8 + (m16 & 7);
#pragma unroll
                    for (int r = 0; r < 4; ++r)
                        Sh[eb + r * 8] = f2bf(acc[mt][nt][r] * sc);
                }
        } else {
#pragma unroll
            for (int mt = 0; mt < 4; ++mt)
#pragma unroll
                for (int nt = 0; nt < 4; ++nt) {
                    int lb = wc * 16 + wr * 8 + (nt >> 1) * 4 + mt;
                    int eb = lb * 512 + (quad & 1) * 256 + ((nt & 1) * 16 + m16) * 8 + (quad >> 1) * 4;
                    unsigned int u0 = f2bf(acc[mt][nt][0]) | ((unsigned int)f2bf(acc[mt][nt][1]) << 16);
                    unsigned int u1 = f2bf(acc[mt][nt][2]) | ((unsigned int)f2bf(acc[mt][nt][3]) << 16);
                    uint2 u; u.x = u0; u.y = u1;
                    *(uint2*)&Sh[eb] = u;
                }
        }
        __syncthreads();
        int b_ = r0 >> 12, n0 = r0 & 4095, hd0 = (c0 >> 6) & 7;
        u16* dst; size_t gb0;
        if (sec == 0)      { dst = Qf; gb0 = (size_t)(n0 >> 5) * 2048; }
        else if (sec == 1) { dst = Kf; gb0 = (size_t)(n0 >> 5) * 2048; }
        else               { dst = Vf; gb0 = (size_t)(n0 >> 6) * 4096; }
        int hl = tid >> 7;                         // head within tile
        size_t gbase = (size_t)(b_ * 8 + hd0 + hl) * 262144 + gb0 + (size_t)(tid & 127) * 64;
#pragma unroll
        for (int s = 0; s < 8; ++s)
            *(int4*)(dst + gbase + s * 8) = *(const int4*)&Sh[tid * 64 + s * 8];
    } else {
#pragma unroll
        for (int mt = 0; mt < 4; ++mt) {
            int R0 = r0 + wr * 64 + mt * 16 + quad * 4;
#pragma unroll
            for (int nt = 0; nt < 4; ++nt) {
                int C = c0 + wc * 64 + nt * 16 + m16;
                float bv = bias[C];
#pragma unroll
                for (int r = 0; r < 4; ++r)
                    Out[(size_t)(R0 + r) * 512 + C] = acc[mt][nt][r] + bv;
            }
        }
    }
}

// ---------------- flash attention: K-split x2 across blocks ----------------
// Round-6 register-double-buffer loop (proven 92.8us at 2 blocks/CU), but each
// block handles only 2048 keys; grid 1024 -> 4 blocks/CU for 2x latency hiding.
// Static-max softmax => partials are additive; combine kernel adds halves.

__device__ __forceinline__ void attn_iter(bf16x8 (&KC)[2][4], bf16x8 (&KN)[2][4],
                                          const bf16x8 (&qf)[4], const bf16x8& onesA,
                                          const fx16& Z,
                                          fx16& O0, fx16& O1, fx16& Lacc,
                                          const u16* __restrict__ Kh,
                                          const u16* __restrict__ Vh,
                                          int lane, int K0) {
    // V^T A-frags for this 64-key block (consumed after exp/pack)
    bf16x8 vf[2][4];
    {
        const u16* vb = Vh + (size_t)(K0 >> 6) * 4096 + lane * 8;
#pragma unroll
        for (int dt = 0; dt < 2; ++dt)
#pragma unroll
            for (int ch = 0; ch < 4; ++ch)
                vf[dt][ch] = ld8(vb + (dt * 4 + ch) * 512);
    }
    // prefetch next iteration's K frags (wrap within this block's 2048-key half)
    {
        int kn0 = (K0 + 64) & 2047;
        const u16* kb = Kh + (size_t)(kn0 >> 5) * 2048 + lane * 8;
#pragma unroll
        for (int dc = 0; dc < 4; ++dc) {
            KN[0][dc] = ld8(kb + dc * 512);
            KN[1][dc] = ld8(kb + 2048 + dc * 512);
        }
    }
    // S^T = K Q^T (C init from persistent zero regs)
    fx16 S0 = Z, S1 = Z;
#pragma unroll
    for (int dc = 0; dc < 4; ++dc) {
        S0 = __builtin_amdgcn_mfma_f32_32x32x16_bf16(KC[0][dc], qf[dc], S0, 0, 0, 0);
        S1 = __builtin_amdgcn_mfma_f32_32x32x16_bf16(KC[1][dc], qf[dc], S1, 0, 0, 0);
    }
    // p = 2^S; packed pairs of consecutive C-regs ARE the B-frags (k-slot permuted V)
    uint32_t pk0[8], pk1[8];
#pragma unroll
    for (int i = 0; i < 8; ++i) {
        pk0[i] = pk2bf(__builtin_amdgcn_exp2f(S0[2 * i]), __builtin_amdgcn_exp2f(S0[2 * i + 1]));
        pk1[i] = pk2bf(__builtin_amdgcn_exp2f(S1[2 * i]), __builtin_amdgcn_exp2f(S1[2 * i + 1]));
    }
    // O^T += V^T P^T ; l += 1^T P^T (ones-MFMA row sums)
#pragma unroll
    for (int c = 0; c < 4; ++c) {
        const uint32_t* pk = (c < 2) ? pk0 : pk1;
        int o = (c & 1) * 4;
        int4 bi; bi.x = (int)pk[o]; bi.y = (int)pk[o + 1]; bi.z = (int)pk[o + 2]; bi.w = (int)pk[o + 3];
        bf16x8 bfrag = __builtin_bit_cast(bf16x8, bi);
        O0 = __builtin_amdgcn_mfma_f32_32x32x16_bf16(vf[0][c], bfrag, O0, 0, 0, 0);
        O1 = __builtin_amdgcn_mfma_f32_32x32x16_bf16(vf[1][c], bfrag, O1, 0, 0, 0);
        Lacc = __builtin_amdgcn_mfma_f32_32x32x16_bf16(onesA, bfrag, Lacc, 0, 0, 0);
    }
}

// grid 1024: bits [qt:5][half:1][bhcode:4]; bh = ((blk&7)<<1)|((blk>>3)&1)
__global__ __launch_bounds__(256, 2) void attn_kernel(const u16* __restrict__ Qf,
                                                      const u16* __restrict__ Kf,
                                                      const u16* __restrict__ Vf,
                                                      float* __restrict__ Part) {
    int tid = threadIdx.x;
    int w = tid >> 6, lane = tid & 63;
    // XCD swizzle: blocks of one (b,h) land on one XCD
    int bh = ((blockIdx.x & 7) << 1) | ((blockIdx.x >> 3) & 1);
    int half = (blockIdx.x >> 4) & 1;
    int qt = blockIdx.x >> 5;

    const u16* Qh = Qf + (size_t)bh * 262144;
    const u16* Kh = Kf + (size_t)bh * 262144 + (size_t)half * 131072;
    const u16* Vh = Vf + (size_t)bh * 262144 + (size_t)half * 131072;

    bf16x8 qf[4];
    {
        const u16* qb = Qh + (size_t)(qt * 4 + w) * 2048 + lane * 8;
#pragma unroll
        for (int dc = 0; dc < 4; ++dc)
            qf[dc] = ld8(qb + dc * 512);
    }

    int4 oi; oi.x = oi.y = oi.z = oi.w = 0x3F803F80;           // bf16 ones
    const bf16x8 onesA = __builtin_bit_cast(bf16x8, oi);
    const fx16 Z = {};
    fx16 O0 = {}, O1 = {}, Lacc = {};

    bf16x8 kA[2][4], kB[2][4];
    {
        const u16* kb = Kh + lane * 8;
#pragma unroll
        for (int dc = 0; dc < 4; ++dc) {
            kA[0][dc] = ld8(kb + dc * 512);
            kA[1][dc] = ld8(kb + 2048 + dc * 512);
        }
    }

    for (int k0 = 0; k0 < 2048; k0 += 128) {
        attn_iter(kA, kB, qf, onesA, Z, O0, O1, Lacc, Kh, Vh, lane, k0);
        attn_iter(kB, kA, qf, onesA, Z, O0, O1, Lacc, Kh, Vh, lane, k0 + 64);
    }

    // write fp32 partials (coalesced 256B per reg-row): Part[blk*4+w][reg 0..32][lane]
    float* dst = Part + (size_t)(blockIdx.x * 4 + w) * 33 * 64 + lane;
#pragma unroll
    for (int r = 0; r < 16; ++r) {
        dst[r * 64]        = O0[r];
        dst[(16 + r) * 64] = O1[r];
    }
    dst[32 * 64] = Lacc[0];
}

// ---------------- combine: add halves, normalize, transpose, store ----------------
// grid 512: bits [qt:5][bhcode:4]; partial blocks p0 = (qt<<5)|bhcode, p1 = p0|16

__global__ __launch_bounds__(256) void combine_kernel(const float* __restrict__ Part,
                                                      u16* __restrict__ Ob) {
    __shared__ __align__(16) u16 Eo[4 * 32 * 68];
    int tid = threadIdx.x;
    int w = tid >> 6, lane = tid & 63;
    int q32 = lane & 31, h = lane >> 5;
    int bhcode = blockIdx.x & 15, qt = blockIdx.x >> 4;
    int bh = ((bhcode & 7) << 1) | (bhcode >> 3);
    int q0 = qt * 128;
    int p0 = (qt << 5) | bhcode, p1 = p0 | 16;

    const float* s0 = Part + (size_t)(p0 * 4 + w) * 33 * 64 + lane;
    const float* s1 = Part + (size_t)(p1 * 4 + w) * 33 * 64 + lane;
    float O0[16], O1[16];
#pragma unroll
    for (int r = 0; r < 16; ++r) {
        O0[r] = s0[r * 64] + s1[r * 64];
        O1[r] = s0[(16 + r) * 64] + s1[(16 + r) * 64];
    }
    float inv = 1.0f / (s0[32 * 64] + s1[32 * 64]);

    int ebase = w * 2176 + q32 * 68;
#pragma unroll
    for (int i = 0; i < 8; ++i) {
        int dbase = 8 * (i >> 1) + (i & 1) * 2 + 4 * h;
        uint32_t v0 = pk2bf(O0[2 * i] * inv, O0[2 * i + 1] * inv);
        uint32_t v1 = pk2bf(O1[2 * i] * inv, O1[2 * i + 1] * inv);
        *(uint32_t*)&Eo[ebase + dbase]      = v0;
        *(uint32_t*)&Eo[ebase + dbase + 32] = v1;
    }
    __syncthreads();
    int row = lane >> 1, halfc = lane & 1;
    int rb = w * 2176 + row * 68 + halfc * 32;
    int b = bh >> 3, hh = bh & 7;
    size_t gb = ((size_t)(b * 4096 + q0 + w * 32 + row)) * 512 + hh * 64 + halfc * 32;
#pragma unroll
    for (int s = 0; s < 4; ++s) {
        uint2 a = *(const uint2*)&Eo[rb + s * 8];
        uint2 c = *(const uint2*)&Eo[rb + s * 8 + 4];
        int4 v; v.x = (int)a.x; v.y = (int)a.y; v.z = (int)c.x; v.w = (int)c.y;
        *(int4*)(Ob + gb + s * 8) = v;
    }
}

// ---------------- launcher ----------------
// Workspace layout (lifetime-overlapped):
//   [0, 34.6M):  Part (attn->combine)  OVERLAPS  x_b@0 (8M) + wqkv_t@8.4M (1.5M),
//                which are dead after gemm0.
//   34.6M: Qfb (8M)   42.99M: Kfb (8M)   51.38M: Vfb (8M)
//   59.77M: Ob (8M)   68.16M: wout_t (0.5M)   total ~68.7 MB

extern "C" void kernel_launch(void* const* d_in, const int* in_sizes, int n_in,
                              void* d_out, int out_size, void* d_ws, size_t ws_size,
                              hipStream_t stream) {
    const float* x     = (const float*)d_in[0];   // [2,4096,512]
    const float* w_qkv = (const float*)d_in[1];   // [512,1536]
    const float* w_out = (const float*)d_in[2];   // [512,512]
    const float* b_out = (const float*)d_in[3];   // [512]
    float* out = (float*)d_out;                   // [2,4096,512] fp32

    char* ws = (char*)d_ws;
    float* Part  = (float*)(ws);                  // 34,603,008 B
    u16* x_b     = (u16*)(ws);                    //  8 MB (dead after gemm0)
    u16* wqkv_t  = (u16*)(ws + 8388608);          //  1.5 MB (dead after gemm0)
    u16* Qfb     = (u16*)(ws + 34603008);         //  8 MB fragment-major (log2-scaled)
    u16* Kfb     = (u16*)(ws + 42991616);         //  8 MB fragment-major
    u16* Vfb     = (u16*)(ws + 51380224);         //  8 MB fragment-major, k-slot permuted
    u16* Ob      = (u16*)(ws + 59768832);         //  8 MB [8192][512]
    u16* wout_t  = (u16*)(ws + 68157440);         //  0.5 MB [512][512]

    cast_x_kernel<<<2048, 256, 0, stream>>>(x, x_b);
    transpose_cast_kernel<<<dim3(32, 8), 256, 0, stream>>>(w_qkv, wqkv_t, w_out, wout_t);
    gemm_kernel<0><<<768, 256, 0, stream>>>(x_b, wqkv_t, Qfb, Kfb, Vfb, nullptr, nullptr, 1536);
    attn_kernel<<<1024, 256, 0, stream>>>(Qfb, Kfb, Vfb, Part);
    combine_kernel<<<512, 256, 0, stream>>>(Part, Ob);
    gemm_kernel<1><<<256, 256, 0, stream>>>(Ob, wout_t, nullptr, nullptr, nullptr, b_out, out, 512);
}

// Round 9
// 217.609 us; speedup vs baseline: 1.0561x; 1.0561x over previous
//
#include <hip/hip_runtime.h>
#include <stdint.h>

typedef unsigned short u16;
typedef __bf16 bf16x8 __attribute__((ext_vector_type(8)));
typedef float fx4 __attribute__((ext_vector_type(4)));
typedef float fx16 __attribute__((ext_vector_type(16)));

// ---------------- helpers ----------------

__device__ __forceinline__ u16 f2bf(float f) {
    unsigned int u = __float_as_uint(f);
    u += 0x7fffu + ((u >> 16) & 1u);   // RNE
    return (u16)(u >> 16);
}

__device__ __forceinline__ bf16x8 ld8(const u16* p) {
    return __builtin_bit_cast(bf16x8, *(const int4*)p);
}

// pack two fp32 -> packed bf16 dword (round-half-up)
__device__ __forceinline__ uint32_t pk2bf(float lo, float hi) {
    uint32_t a = __float_as_uint(lo) + 0x8000u;
    uint32_t b = __float_as_uint(hi) + 0x8000u;
    return __builtin_amdgcn_perm(b, a, 0x07060302u);
}

// async global->LDS, 16B per lane: HW writes lds_base + lane*16
typedef __attribute__((address_space(3))) uint32_t lds_u32;
typedef __attribute__((address_space(1))) const uint32_t glb_u32;
__device__ __forceinline__ void glds16(const u16* g, u16* l) {
    __builtin_amdgcn_global_load_lds((glb_u32*)g, (lds_u32*)l, 16, 0, 0);
}

// ---------------- kernel 0a: cast x -> bf16 ----------------

__global__ __launch_bounds__(256) void cast_x_kernel(const float* __restrict__ x,
                                                     u16* __restrict__ xb) {
    int idx = blockIdx.x * 256 + threadIdx.x;   // 8 elems per thread
    const float4* p = (const float4*)(x + (size_t)idx * 8);
    float4 a = p[0], b = p[1];
    int4 v;
    v.x = (int)pk2bf(a.x, a.y); v.y = (int)pk2bf(a.z, a.w);
    v.z = (int)pk2bf(b.x, b.y); v.w = (int)pk2bf(b.z, b.w);
    *(int4*)(xb + (size_t)idx * 8) = v;
}

// ---------------- kernel 0b: transpose + cast both weight matrices ----------------

__global__ __launch_bounds__(256) void transpose_cast_kernel(const float* __restrict__ w_qkv,
                                                             u16* __restrict__ wqkv_t,
                                                             const float* __restrict__ w_out,
                                                             u16* __restrict__ wout_t) {
    __shared__ float T[64][65];
    int t = threadIdx.x;
    int bx = blockIdx.x;
    const float* in; u16* out; int NR = 512, NC;
    if (bx < 24) { in = w_qkv; out = wqkv_t; NC = 1536; }
    else         { in = w_out; out = wout_t; NC = 512; bx -= 24; }
    int i0 = blockIdx.y * 64, j0 = bx * 64;
    int r = t >> 4, cc = t & 15;
#pragma unroll
    for (int j = 0; j < 4; ++j) {
        int row = r + j * 16;
        float4 v = *(const float4*)(in + (size_t)(i0 + row) * NC + j0 + cc * 4);
        T[row][cc * 4 + 0] = v.x; T[row][cc * 4 + 1] = v.y;
        T[row][cc * 4 + 2] = v.z; T[row][cc * 4 + 3] = v.w;
    }
    __syncthreads();
#pragma unroll
    for (int j = 0; j < 4; ++j) {
        int jr = r + j * 16;
        unsigned int u0 = f2bf(T[cc * 4 + 0][jr]) | ((unsigned int)f2bf(T[cc * 4 + 1][jr]) << 16);
        unsigned int u1 = f2bf(T[cc * 4 + 2][jr]) | ((unsigned int)f2bf(T[cc * 4 + 3][jr]) << 16);
        uint2 u; u.x = u0; u.y = u1;
        *(uint2*)(out + (size_t)(j0 + jr) * NR + i0 + cc * 4) = u;
    }
}

// ---------------- GEMM: C[M,Ncols] = A[M,512] * Bt[Ncols,512]^T ----------------

#define QSCALE 0.180336880f   // (1/8) * log2(e): logits in log2 domain

template<int MODE>
__global__ __launch_bounds__(256) void gemm_kernel(const u16* __restrict__ A,
                                                   const u16* __restrict__ Bt,
                                                   u16* __restrict__ Qf,
                                                   u16* __restrict__ Kf,
                                                   u16* __restrict__ Vf,
                                                   const float* __restrict__ bias,
                                                   float* __restrict__ Out,
                                                   int Ncols) {
    __shared__ __align__(16) u16 Sh[16384];
    int tid = threadIdx.x;
    int w = tid >> 6, lane = tid & 63;
    int m16 = lane & 15, quad = lane >> 4;
    int ntn = Ncols / 128;
    int g = blockIdx.x;
    int xcd = g & 7, j = g >> 3;
    int by = xcd + 8 * (j / ntn);
    int bx = j % ntn;
    int r0 = by * 128, c0 = bx * 128;
    int wr = w >> 1, wc = w & 1;
    int lrow = lane >> 2, lchk = (lane & 3) * 8;

    fx4 acc[4][4] = {};

    for (int k0 = 0; k0 < 512; k0 += 32) {
        __syncthreads();
#pragma unroll
        for (int jj = 0; jj < 2; ++jj) {
            int rw = jj * 64 + w * 16;
            glds16(A  + (size_t)(r0 + rw + lrow) * 512 + k0 + lchk, &Sh[rw * 32]);
            glds16(Bt + (size_t)(c0 + rw + lrow) * 512 + k0 + lchk, &Sh[4096 + rw * 32]);
        }
        __syncthreads();
        bf16x8 af[4], bfr[4];
#pragma unroll
        for (int t = 0; t < 4; ++t) {
            af[t]  = ld8(&Sh[(wr * 64 + t * 16 + m16) * 32 + quad * 8]);
            bfr[t] = ld8(&Sh[4096 + (wc * 64 + t * 16 + m16) * 32 + quad * 8]);
        }
#pragma unroll
        for (int mt = 0; mt < 4; ++mt)
#pragma unroll
            for (int nt = 0; nt < 4; ++nt)
                acc[mt][nt] = __builtin_amdgcn_mfma_f32_16x16x32_bf16(af[mt], bfr[nt], acc[mt][nt], 0, 0, 0);
    }

    if (MODE == 0) {
        int sec = c0 >> 9;                         // 0=q 1=k 2=v
        __syncthreads();
        if (sec <= 1) {
            float sc = (sec == 0) ? QSCALE : 1.0f;
#pragma unroll
            for (int mt = 0; mt < 4; ++mt)
#pragma unroll
                for (int nt = 0; nt < 4; ++nt) {
                    int lb = wc * 16 + (wr * 2 + (mt >> 1)) * 4 + nt;
                    int eb = lb * 512 + (m16 >> 3) * 256 + ((mt & 1) * 16 + quad * 4) * 8 + (m16 & 7);
#pragma unroll
                    for (int r = 0; r < 4; ++r)
                        Sh[eb + r * 8] = f2bf(acc[mt][nt][r] * sc);
                }
        } else {
#pragma unroll
            for (int mt = 0; mt < 4; ++mt)
#pragma unroll
                for (int nt = 0; nt < 4; ++nt) {
                    int lb = wc * 16 + wr * 8 + (nt >> 1) * 4 + mt;
                    int eb = lb * 512 + (quad & 1) * 256 + ((nt & 1) * 16 + m16) * 8 + (quad >> 1) * 4;
                    unsigned int u0 = f2bf(acc[mt][nt][0]) | ((unsigned int)f2bf(acc[mt][nt][1]) << 16);
                    unsigned int u1 = f2bf(acc[mt][nt][2]) | ((unsigned int)f2bf(acc[mt][nt][3]) << 16);
                    uint2 u; u.x = u0; u.y = u1;
                    *(uint2*)&Sh[eb] = u;
                }
        }
        __syncthreads();
        int b_ = r0 >> 12, n0 = r0 & 4095, hd0 = (c0 >> 6) & 7;
        u16* dst; size_t gb0;
        if (sec == 0)      { dst = Qf; gb0 = (size_t)(n0 >> 5) * 2048; }
        else if (sec == 1) { dst = Kf; gb0 = (size_t)(n0 >> 5) * 2048; }
        else               { dst = Vf; gb0 = (size_t)(n0 >> 6) * 4096; }
        int hl = tid >> 7;
        size_t gbase = (size_t)(b_ * 8 + hd0 + hl) * 262144 + gb0 + (size_t)(tid & 127) * 64;
#pragma unroll
        for (int s = 0; s < 8; ++s)
            *(int4*)(dst + gbase + s * 8) = *(const int4*)&Sh[tid * 64 + s * 8];
    } else {
#pragma unroll
        for (int mt = 0; mt < 4; ++mt) {
            int R0 = r0 + wr * 64 + mt * 16 + quad * 4;
#pragma unroll
            for (int nt = 0; nt < 4; ++nt) {
                int C = c0 + wc * 64 + nt * 16 + m16;
                float bv = bias[C];
#pragma unroll
                for (int r = 0; r < 4; ++r)
                    Out[(size_t)(R0 + r) * 512 + C] = acc[mt][nt][r] + bv;
            }
        }
    }
}

// ---------------- flash attention: slim waves, 32-key iters, K-split x2 ----------------
// grid 2048 x 128thr: bits [qt:6][half:1][bhcode:4]. Each wave: 32 queries x 2048 keys.
// Register diet vs r8: S 16 (one 32x32 tile), vf 16, K dbuf 2x16, no Z, no Lacc
// (l = 16 VALU adds/iter + one end shfl). Target <=~140 total regs -> 3-4 waves/SIMD.

__device__ __forceinline__ void attn_iter32(bf16x8 (&KC)[4], bf16x8 (&KN)[4],
                                            const bf16x8 (&qf)[4],
                                            fx16& O0, fx16& O1, float& l_c,
                                            const u16* __restrict__ Kh,
                                            const u16* __restrict__ Vh,
                                            int lane, int K0) {
    // V^T A-frags: 2 d-halves x 2 k-chunks of this 32-key group (consumed after exp)
    bf16x8 vf[2][2];
    {
        const u16* vb = Vh + (size_t)(K0 >> 6) * 4096 + ((K0 >> 4) & 2) * 512 + lane * 8;
#pragma unroll
        for (int dt = 0; dt < 2; ++dt)
#pragma unroll
            for (int ch = 0; ch < 2; ++ch)
                vf[dt][ch] = ld8(vb + (dt * 4 + ch) * 512);
    }
    // prefetch next 32-key K group (wrap within the 2048-key half)
    {
        int kn = (K0 + 32) & 2047;
        const u16* kb = Kh + (size_t)(kn >> 5) * 2048 + lane * 8;
#pragma unroll
        for (int dc = 0; dc < 4; ++dc)
            KN[dc] = ld8(kb + dc * 512);
    }
    // S^T = K Q^T : one 32x32 tile
    fx16 S = {};
#pragma unroll
    for (int dc = 0; dc < 4; ++dc)
        S = __builtin_amdgcn_mfma_f32_32x32x16_bf16(KC[dc], qf[dc], S, 0, 0, 0);
    // p = 2^S; packed pairs of consecutive C-regs ARE the B-frags; l += sum(p)
    float ps = 0.0f;
    uint32_t pk[8];
#pragma unroll
    for (int i = 0; i < 8; ++i) {
        float a0 = __builtin_amdgcn_exp2f(S[2 * i]);
        float a1 = __builtin_amdgcn_exp2f(S[2 * i + 1]);
        ps += a0 + a1;
        pk[i] = pk2bf(a0, a1);
    }
    l_c += ps;
    // O^T += V^T P^T : 2 k-chunks x 2 d-halves
#pragma unroll
    for (int c = 0; c < 2; ++c) {
        int4 bi; bi.x = (int)pk[c * 4]; bi.y = (int)pk[c * 4 + 1];
        bi.z = (int)pk[c * 4 + 2]; bi.w = (int)pk[c * 4 + 3];
        bf16x8 bfrag = __builtin_bit_cast(bf16x8, bi);
        O0 = __builtin_amdgcn_mfma_f32_32x32x16_bf16(vf[0][c], bfrag, O0, 0, 0, 0);
        O1 = __builtin_amdgcn_mfma_f32_32x32x16_bf16(vf[1][c], bfrag, O1, 0, 0, 0);
    }
}

__global__ __launch_bounds__(128, 3) void attn_kernel(const u16* __restrict__ Qf,
                                                      const u16* __restrict__ Kf,
                                                      const u16* __restrict__ Vf,
                                                      float* __restrict__ Part) {
    int tid = threadIdx.x;
    int w = tid >> 6, lane = tid & 63;
    // XCD swizzle: blocks of one (b,h) land on one XCD
    int bh = ((blockIdx.x & 7) << 1) | ((blockIdx.x >> 3) & 1);
    int half = (blockIdx.x >> 4) & 1;
    int qt = blockIdx.x >> 5;                     // 0..63, q-tile of 64

    const u16* Qh = Qf + (size_t)bh * 262144;
    const u16* Kh = Kf + (size_t)bh * 262144 + (size_t)half * 131072;
    const u16* Vh = Vf + (size_t)bh * 262144 + (size_t)half * 131072;

    bf16x8 qf[4];
    {
        const u16* qb = Qh + (size_t)(qt * 2 + w) * 2048 + lane * 8;
#pragma unroll
        for (int dc = 0; dc < 4; ++dc)
            qf[dc] = ld8(qb + dc * 512);
    }

    fx16 O0 = {}, O1 = {};
    float l_c = 0.0f;

    bf16x8 kA[4], kB[4];
    {
        const u16* kb = Kh + lane * 8;
#pragma unroll
        for (int dc = 0; dc < 4; ++dc)
            kA[dc] = ld8(kb + dc * 512);
    }

    for (int k0 = 0; k0 < 2048; k0 += 64) {
        attn_iter32(kA, kB, qf, O0, O1, l_c, Kh, Vh, lane, k0);
        attn_iter32(kB, kA, qf, O0, O1, l_c, Kh, Vh, lane, k0 + 32);
    }

    // finish l: lane and lane^32 hold complementary key-halves of the same query
    l_c += __shfl_xor(l_c, 32);

    // write fp32 partials, coalesced 256B rows: Part[wave][reg 0..32][lane]
    float* dst = Part + (size_t)(blockIdx.x * 2 + w) * 2112 + lane;
#pragma unroll
    for (int r = 0; r < 16; ++r) {
        dst[r * 64]        = O0[r];
        dst[(16 + r) * 64] = O1[r];
    }
    dst[32 * 64] = l_c;
}

// ---------------- combine: add key-halves, normalize, transpose, store ----------------
// grid 1024 x 128thr: bits [qt:6][bhcode:4]

__global__ __launch_bounds__(128) void combine_kernel(const float* __restrict__ Part,
                                                      u16* __restrict__ Ob) {
    __shared__ __align__(16) u16 Eo[2 * 32 * 68];
    int tid = threadIdx.x;
    int w = tid >> 6, lane = tid & 63;
    int q32 = lane & 31, h = lane >> 5;
    int bhcode = blockIdx.x & 15, qt = blockIdx.x >> 4;
    int bh = ((bhcode & 7) << 1) | (bhcode >> 3);
    int q0 = qt * 64;
    int p0 = ((qt << 5) | bhcode) * 2 + w;
    int p1 = ((qt << 5) | 16 | bhcode) * 2 + w;

    const float* s0 = Part + (size_t)p0 * 2112 + lane;
    const float* s1 = Part + (size_t)p1 * 2112 + lane;
    float O0[16], O1[16];
#pragma unroll
    for (int r = 0; r < 16; ++r) {
        O0[r] = s0[r * 64] + s1[r * 64];
        O1[r] = s0[(16 + r) * 64] + s1[(16 + r) * 64];
    }
    float inv = 1.0f / (s0[32 * 64] + s1[32 * 64]);

    int ebase = w * 2176 + q32 * 68;
#pragma unroll
    for (int i = 0; i < 8; ++i) {
        int dbase = 8 * (i >> 1) + (i & 1) * 2 + 4 * h;
        uint32_t v0 = pk2bf(O0[2 * i] * inv, O0[2 * i + 1] * inv);
        uint32_t v1 = pk2bf(O1[2 * i] * inv, O1[2 * i + 1] * inv);
        *(uint32_t*)&Eo[ebase + dbase]      = v0;
        *(uint32_t*)&Eo[ebase + dbase + 32] = v1;
    }
    asm volatile("s_waitcnt lgkmcnt(0)" ::: "memory");   // Eo slice is wave-private
    int row = lane >> 1, halfc = lane & 1;
    int rb = w * 2176 + row * 68 + halfc * 32;
    int b = bh >> 3, hh = bh & 7;
    size_t gb = ((size_t)(b * 4096 + q0 + w * 32 + row)) * 512 + hh * 64 + halfc * 32;
#pragma unroll
    for (int s = 0; s < 4; ++s) {
        uint2 a = *(const uint2*)&Eo[rb + s * 8];
        uint2 c = *(const uint2*)&Eo[rb + s * 8 + 4];
        int4 v; v.x = (int)a.x; v.y = (int)a.y; v.z = (int)c.x; v.w = (int)c.y;
        *(int4*)(Ob + gb + s * 8) = v;
    }
}

// ---------------- launcher ----------------
// Workspace (lifetime-overlapped): Part [0,34.6M) overlaps x_b(8M)+wqkv_t(1.5M)
// which die after gemm0. Then Qfb/Kfb/Vfb/Ob/wout_t. Total ~68.7 MB.

extern "C" void kernel_launch(void* const* d_in, const int* in_sizes, int n_in,
                              void* d_out, int out_size, void* d_ws, size_t ws_size,
                              hipStream_t stream) {
    const float* x     = (const float*)d_in[0];   // [2,4096,512]
    const float* w_qkv = (const float*)d_in[1];   // [512,1536]
    const float* w_out = (const float*)d_in[2];   // [512,512]
    const float* b_out = (const float*)d_in[3];   // [512]
    float* out = (float*)d_out;                   // [2,4096,512] fp32

    char* ws = (char*)d_ws;
    float* Part  = (float*)(ws);                  // 4096 waves x 2112 fp32 = 34,603,008 B
    u16* x_b     = (u16*)(ws);                    //  8 MB (dead after gemm0)
    u16* wqkv_t  = (u16*)(ws + 8388608);          //  1.5 MB (dead after gemm0)
    u16* Qfb     = (u16*)(ws + 34603008);         //  8 MB fragment-major (log2-scaled)
    u16* Kfb     = (u16*)(ws + 42991616);         //  8 MB fragment-major
    u16* Vfb     = (u16*)(ws + 51380224);         //  8 MB fragment-major, k-slot permuted
    u16* Ob      = (u16*)(ws + 59768832);         //  8 MB [8192][512]
    u16* wout_t  = (u16*)(ws + 68157440);         //  0.5 MB [512][512]

    cast_x_kernel<<<2048, 256, 0, stream>>>(x, x_b);
    transpose_cast_kernel<<<dim3(32, 8), 256, 0, stream>>>(w_qkv, wqkv_t, w_out, wout_t);
    gemm_kernel<0><<<768, 256, 0, stream>>>(x_b, wqkv_t, Qfb, Kfb, Vfb, nullptr, nullptr, 1536);
    attn_kernel<<<2048, 128, 0, stream>>>(Qfb, Kfb, Vfb, Part);
    combine_kernel<<<1024, 128, 0, stream>>>(Part, Ob);
    gemm_kernel<1><<<256, 256, 0, stream>>>(Ob, wout_t, nullptr, nullptr, nullptr, b_out, out, 512);
}